// Round 2
// baseline (103.751 us; speedup 1.0000x reference)
//
#include <hip/hip_runtime.h>
#include <hip/hip_bf16.h>

typedef __attribute__((ext_vector_type(8))) short short8;
typedef __attribute__((ext_vector_type(4))) short short4_t;
typedef __attribute__((ext_vector_type(4))) float f32x4;

#define B_SZ 64
#define T_SZ 8192
#define D_SZ 128
#define U_SZ 128
#define T_TILE 128
#define N_TILES (T_SZ / T_TILE)   /* 64 tiles per batch */
#define P_STRIDE 132              /* c[128] + m + s, padded */
#define XT_LD 136                 /* bf16 row stride: 272B -> 2-way bank alias (free) */

__device__ __forceinline__ unsigned short f2bf(float f) {
  // round-to-nearest-even fp32 -> bf16
  unsigned int u = __builtin_bit_cast(unsigned int, f);
  u += 0x7fffu + ((u >> 16) & 1u);
  return (unsigned short)(u >> 16);
}

__device__ __forceinline__ float bf2f(unsigned short s) {
  return __builtin_bit_cast(float, (unsigned int)s << 16);
}

__device__ __forceinline__ float fast_tanh(float x) {
  // tanh(x) = 1 - 2/(e^{2x}+1); saturates correctly at +-inf
  float e = __expf(2.0f * x);
  return 1.0f - 2.0f * __builtin_amdgcn_rcpf(e + 1.0f);
}

// ---------------------------------------------------------------------------
// Kernel 0: W [d][u] fp32 -> Wt [u][d] bf16 in workspace (once, tiny)
// ---------------------------------------------------------------------------
__global__ void k_prep(const float* __restrict__ wk, unsigned short* __restrict__ wt) {
  int i = blockIdx.x * 256 + threadIdx.x;     // 16384 elements
  if (i < D_SZ * U_SZ) {
    int d = i >> 7, u = i & 127;
    wt[u * D_SZ + d] = f2bf(wk[i]);
  }
}

// ---------------------------------------------------------------------------
// Kernel 1: per (b, T-tile of 128): logits via bf16 MFMA (A from global fp32,
// B = Wt from global, L1/L2-hot), tile softmax partials, weighted context
// from the LDS-staged bf16 x-tile (NO second global read of x).
// ---------------------------------------------------------------------------
__global__ __launch_bounds__(256, 4) void k_partial(
    const float* __restrict__ x, const unsigned short* __restrict__ wt_g,
    const float* __restrict__ wb, const float* __restrict__ v,
    const float* __restrict__ vb, float* __restrict__ pbuf)
{
  __shared__ unsigned short xt[T_TILE][XT_LD];  // 34816 B: bf16 x-tile
  __shared__ float uni[8 * D_SZ];               // 4 KB: wb/v (phase 1) then cpar (phase 3)
  __shared__ float logits[T_TILE];
  __shared__ float pw[T_TILE];
  __shared__ float msum[2];

  float* wb_s = uni;              // [128], dead before cpar is written
  float* v_s  = uni + U_SZ;       // [128]
  float (*cpar)[D_SZ] = (float(*)[D_SZ])uni;    // [8][128], phase 3 only

  const int tid  = threadIdx.x;
  const int bidx = blockIdx.x;
  const int b    = bidx >> 6;       // /N_TILES
  const int tile = bidx & 63;

  if (tid < U_SZ) { wb_s[tid] = wb[tid]; v_s[tid] = v[tid]; }

  const int w  = tid >> 6;          // wave 0..3, owns rows w*32..w*32+31
  const int l  = tid & 63;
  const int lr = l & 15;            // A-row / B-col / D-col lane index
  const int lh = l >> 4;            // 0..3 -> k-subchunk / D-row group
  const size_t xbase = ((size_t)b * T_SZ + (size_t)tile * T_TILE) * D_SZ;

  // A fragments: 2 row-subtiles x 4 k-tiles, from global fp32; also stage
  // the bf16 tile into LDS for the weighted-sum phase.
  short8 afrag[2][4];
#pragma unroll
  for (int s = 0; s < 2; ++s) {
    const int row = w * 32 + s * 16 + lr;
    const float* xr = x + xbase + (size_t)row * D_SZ;
#pragma unroll
    for (int kt = 0; kt < 4; ++kt) {
      const float4 f0 = *(const float4*)(xr + kt * 32 + lh * 8);
      const float4 f1 = *(const float4*)(xr + kt * 32 + lh * 8 + 4);
      short8 a;
      a[0] = (short)f2bf(f0.x); a[1] = (short)f2bf(f0.y);
      a[2] = (short)f2bf(f0.z); a[3] = (short)f2bf(f0.w);
      a[4] = (short)f2bf(f1.x); a[5] = (short)f2bf(f1.y);
      a[6] = (short)f2bf(f1.z); a[7] = (short)f2bf(f1.w);
      afrag[s][kt] = a;
      *(short8*)&xt[row][kt * 32 + lh * 8] = a;
    }
  }
  __syncthreads();

  // logit accumulators per lane (partial row-sums over this lane's u-column)
  float lg0[4] = {0.f, 0.f, 0.f, 0.f};
  float lg1[4] = {0.f, 0.f, 0.f, 0.f};

#pragma unroll
  for (int ut = 0; ut < 8; ++ut) {
    f32x4 acc0 = {0.f, 0.f, 0.f, 0.f};
    f32x4 acc1 = {0.f, 0.f, 0.f, 0.f};
#pragma unroll
    for (int kt = 0; kt < 4; ++kt) {
      // B fragment straight from global Wt[u][d]; 32 KB total, L1/L2-hot.
      short8 bfrag = *(const short8*)&wt_g[(size_t)(ut * 16 + lr) * D_SZ + kt * 32 + lh * 8];
      acc0 = __builtin_amdgcn_mfma_f32_16x16x32_bf16(afrag[0][kt], bfrag, acc0, 0, 0, 0);
      acc1 = __builtin_amdgcn_mfma_f32_16x16x32_bf16(afrag[1][kt], bfrag, acc1, 0, 0, 0);
    }
    const float wbv = wb_s[ut * 16 + lr];
    const float vv  = v_s[ut * 16 + lr];
#pragma unroll
    for (int r = 0; r < 4; ++r) {
      lg0[r] += fast_tanh(acc0[r] + wbv) * vv;
      lg1[r] += fast_tanh(acc1[r] + wbv) * vv;
    }
  }

  // reduce over the 16 u-columns (lane bits 0..3)
#pragma unroll
  for (int m = 1; m <= 8; m <<= 1) {
#pragma unroll
    for (int r = 0; r < 4; ++r) {
      lg0[r] += __shfl_xor(lg0[r], m, 64);
      lg1[r] += __shfl_xor(lg1[r], m, 64);
    }
  }
  const float vbias = vb[0];
  if (lr == 0) {
#pragma unroll
    for (int r = 0; r < 4; ++r) {
      logits[w * 32 +      lh * 4 + r] = lg0[r] + vbias;
      logits[w * 32 + 16 + lh * 4 + r] = lg1[r] + vbias;
    }
  }
  __syncthreads();

  // tile softmax partials (wave 0)
  if (tid < 64) {
    float l0 = logits[tid], l1 = logits[64 + tid];
    float mx = fmaxf(l0, l1);
#pragma unroll
    for (int m = 1; m <= 32; m <<= 1) mx = fmaxf(mx, __shfl_xor(mx, m, 64));
    float p0 = __expf(l0 - mx), p1 = __expf(l1 - mx);
    float ss = p0 + p1;
#pragma unroll
    for (int m = 1; m <= 32; m <<= 1) ss += __shfl_xor(ss, m, 64);
    pw[tid] = p0; pw[64 + tid] = p1;
    if (tid == 0) { msum[0] = mx; msum[1] = ss; }
  }
  __syncthreads();   // also closes the wb_s/v_s lifetime before cpar reuse

  // weighted partial context from LDS bf16 tile:
  // thread = (g8 = tid>>5) t-chunk of 16, (dq = tid&31) 4 d-columns
  const int g8 = tid >> 5, dq = tid & 31, d0 = dq * 4;
  f32x4 c = {0.f, 0.f, 0.f, 0.f};
#pragma unroll
  for (int i = 0; i < 16; ++i) {
    const int t = g8 * 16 + i;
    const float p = pw[t];
    short4_t xv = *(const short4_t*)&xt[t][d0];
    c[0] = fmaf(p, bf2f((unsigned short)xv[0]), c[0]);
    c[1] = fmaf(p, bf2f((unsigned short)xv[1]), c[1]);
    c[2] = fmaf(p, bf2f((unsigned short)xv[2]), c[2]);
    c[3] = fmaf(p, bf2f((unsigned short)xv[3]), c[3]);
  }
  *(f32x4*)&cpar[g8][d0] = c;
  __syncthreads();

  float* pb = pbuf + (size_t)bidx * P_STRIDE;
  if (tid < 128) {
    float cs = 0.f;
#pragma unroll
    for (int g = 0; g < 8; ++g) cs += cpar[g][tid];
    pb[tid] = cs;
  } else if (tid == 128) pb[128] = msum[0];
  else if (tid == 129) pb[129] = msum[1];
}

// ---------------------------------------------------------------------------
// Kernel 2: combine 64 tile-partials per batch with global softmax rescale
// ---------------------------------------------------------------------------
__global__ __launch_bounds__(128) void k_combine(const float* __restrict__ pbuf,
                                                 float* __restrict__ out)
{
  const int b = blockIdx.x, tid = threadIdx.x;
  __shared__ float sc[N_TILES];
  __shared__ float stot_s;
  const float* pb = pbuf + (size_t)b * N_TILES * P_STRIDE;

  if (tid < 64) {
    float m = pb[tid * P_STRIDE + 128];
    float mx = m;
#pragma unroll
    for (int k = 1; k <= 32; k <<= 1) mx = fmaxf(mx, __shfl_xor(mx, k, 64));
    float e = __expf(m - mx);
    float s = pb[tid * P_STRIDE + 129] * e;
    float st = s;
#pragma unroll
    for (int k = 1; k <= 32; k <<= 1) st += __shfl_xor(st, k, 64);
    sc[tid] = e;
    if (tid == 0) stot_s = st;
  }
  __syncthreads();

  float c = 0.0f;
#pragma unroll 8
  for (int i = 0; i < N_TILES; ++i) c = fmaf(pb[(size_t)i * P_STRIDE + tid], sc[i], c);
  out[b * D_SZ + tid] = c / stot_s;
}

// ---------------------------------------------------------------------------
extern "C" void kernel_launch(void* const* d_in, const int* in_sizes, int n_in,
                              void* d_out, int out_size, void* d_ws, size_t ws_size,
                              hipStream_t stream) {
  const float* x  = (const float*)d_in[0];  // [B,T,D]
  const float* wk = (const float*)d_in[1];  // [D,U]
  const float* wb = (const float*)d_in[2];  // [U]
  const float* vk = (const float*)d_in[3];  // [U,1]
  const float* vb = (const float*)d_in[4];  // [1]
  float* out = (float*)d_out;               // [B,D]

  unsigned short* wt = (unsigned short*)d_ws;               // 32 KB bf16 Wt[u][d]
  float* pbuf = (float*)((char*)d_ws + 32768);              // 4096 * 132 floats

  k_prep<<<64, 256, 0, stream>>>(wk, wt);
  k_partial<<<B_SZ * N_TILES, 256, 0, stream>>>(x, wt, wb, vk, vb, pbuf);
  k_combine<<<B_SZ, 128, 0, stream>>>(pbuf, out);
}